// Round 1
// baseline (450.747 us; speedup 1.0000x reference)
//
#include <hip/hip_runtime.h>
#include <math.h>

#define NUM_MODELS 5
#define LABELS 1000

// One 64-lane wave per batch element. Each lane holds 16 row elements in
// registers (4x float4, fully coalesced: consecutive lanes -> consecutive
// float4). Per model: wave argmax (min-index tie-break to match jnp.argmax),
// wave sum of exp(x - max). Then exact scan-vote over the 5 labels, re-gather
// logits[j,b,pred] (tiny, mostly L2), and one float atomicAdd per wave.
__global__ __launch_bounds__(256) void self_loss_kernel(
    const float* __restrict__ logits, float* __restrict__ out, int B) {
  const int wave = threadIdx.x >> 6;
  const int lane = threadIdx.x & 63;
  const int b = blockIdx.x * 4 + wave;
  if (b >= B) return;

  int   labs[NUM_MODELS];
  float ms[NUM_MODELS];
  float lse[NUM_MODELS];

  #pragma unroll
  for (int j = 0; j < NUM_MODELS; ++j) {
    const float* row = logits + ((size_t)j * B + b) * LABELS;
    float v[16];
    #pragma unroll
    for (int k = 0; k < 4; ++k) {
      const int idx = 4 * (lane + 64 * k);
      if (idx < LABELS) {
        const float4 f = *reinterpret_cast<const float4*>(row + idx);
        v[4 * k + 0] = f.x; v[4 * k + 1] = f.y;
        v[4 * k + 2] = f.z; v[4 * k + 3] = f.w;
      } else {
        // exp(-inf - m) = 0, and -inf never wins the max (lane's k=0 chunk
        // is always in-bounds since 4*lane <= 252 < 1000).
        v[4 * k + 0] = v[4 * k + 1] = v[4 * k + 2] = v[4 * k + 3] = -INFINITY;
      }
    }

    // Local argmax. Iteration order is strictly index-increasing within a
    // lane, so strict '>' keeps the lowest index on ties.
    float m = v[0];
    int   am = 4 * lane;
    #pragma unroll
    for (int k = 0; k < 4; ++k) {
      #pragma unroll
      for (int e = 0; e < 4; ++e) {
        const int idx = 4 * (lane + 64 * k) + e;
        if (v[4 * k + e] > m) { m = v[4 * k + e]; am = idx; }
      }
    }
    // Wave butterfly argmax; min-index tie-break (matches jnp.argmax).
    #pragma unroll
    for (int off = 32; off > 0; off >>= 1) {
      const float om = __shfl_xor(m, off);
      const int   oa = __shfl_xor(am, off);
      if (om > m || (om == m && oa < am)) { m = om; am = oa; }
    }

    // Sum of exp(x - m) from registers (no re-read).
    float s = 0.f;
    #pragma unroll
    for (int i = 0; i < 16; ++i) s += __expf(v[i] - m);
    #pragma unroll
    for (int off = 32; off > 0; off >>= 1) s += __shfl_xor(s, off);

    labs[j] = am;
    ms[j]   = m;
    lse[j]  = logf(s);
  }

  // Exact reference voting semantics: after adding model j's label, its count
  // is c = 1 + #{k < j : lab_k == lab_j}; winner updates only on c > best.
  int best_label = 0, best_count = 0;
  #pragma unroll
  for (int j = 0; j < NUM_MODELS; ++j) {
    int c = 1;
    #pragma unroll
    for (int k = 0; k < j; ++k) c += (labs[k] == labs[j]) ? 1 : 0;
    if (c > best_count) { best_count = c; best_label = labs[j]; }
  }

  // Gather logits[j, b, best_label] (lane j does model j's load).
  float picked = 0.f;
  if (lane < NUM_MODELS)
    picked = logits[((size_t)lane * B + b) * LABELS + best_label];

  // tot = sum_j logp[j, b, pred] ; loss contribution = -tot / B.
  float tot = 0.f;
  #pragma unroll
  for (int j = 0; j < NUM_MODELS; ++j)
    tot += __shfl(picked, j) - ms[j] - lse[j];

  if (lane == 0) atomicAdd(out, -tot / (float)B);
}

extern "C" void kernel_launch(void* const* d_in, const int* in_sizes, int n_in,
                              void* d_out, int out_size, void* d_ws, size_t ws_size,
                              hipStream_t stream) {
  const float* logits = (const float*)d_in[0];
  float* out = (float*)d_out;
  const int n = in_sizes[0];
  const int B = n / (NUM_MODELS * LABELS);

  // Harness does not re-zero d_out between timed replays.
  hipMemsetAsync(d_out, 0, sizeof(float), stream);

  const int blocks = (B + 3) / 4;  // 4 waves/block, one wave per batch element
  self_loss_kernel<<<blocks, 256, 0, stream>>>(logits, out, B);
}

// Round 2
// 125.836 us; speedup vs baseline: 3.5820x; 3.5820x over previous
//
#include <hip/hip_runtime.h>
#include <math.h>

#define NUM_MODELS 5
#define LABELS 1000

// Issue one model-row's 4 coalesced float4 loads into a named register buffer.
// k and the buffer name are compile-time -> SROA keeps everything in VGPRs.
#define LOAD_ROW(j_, v_)                                                   \
  {                                                                        \
    const float* row_ = logits + ((size_t)(j_) * B + b) * LABELS;          \
    _Pragma("unroll")                                                      \
    for (int k = 0; k < 4; ++k) {                                          \
      const int idx_ = 4 * (lane + 64 * k);                                \
      if (idx_ < LABELS) {                                                 \
        const float4 f_ = *reinterpret_cast<const float4*>(row_ + idx_);   \
        v_[4*k+0] = f_.x; v_[4*k+1] = f_.y;                                \
        v_[4*k+2] = f_.z; v_[4*k+3] = f_.w;                                \
      } else {                                                             \
        v_[4*k+0] = v_[4*k+1] = v_[4*k+2] = v_[4*k+3] = -INFINITY;         \
      }                                                                    \
    }                                                                      \
  }

// Wave argmax (min-index tie-break, matches jnp.argmax) + logsumexp of the
// 16 register-resident elements. j_ is compile-time under full unroll.
#define PROCESS_ROW(j_, v_)                                                \
  {                                                                        \
    float m_ = v_[0];                                                      \
    int   am_ = 4 * lane;                                                  \
    _Pragma("unroll")                                                      \
    for (int k = 0; k < 4; ++k) {                                          \
      _Pragma("unroll")                                                    \
      for (int e = 0; e < 4; ++e) {                                        \
        const int idx_ = 4 * (lane + 64 * k) + e;                          \
        if (v_[4*k+e] > m_) { m_ = v_[4*k+e]; am_ = idx_; }                \
      }                                                                    \
    }                                                                      \
    _Pragma("unroll")                                                      \
    for (int off = 32; off > 0; off >>= 1) {                               \
      const float om_ = __shfl_xor(m_, off);                               \
      const int   oa_ = __shfl_xor(am_, off);                              \
      if (om_ > m_ || (om_ == m_ && oa_ < am_)) { m_ = om_; am_ = oa_; }   \
    }                                                                      \
    float s_ = 0.f;                                                        \
    _Pragma("unroll")                                                      \
    for (int i = 0; i < 16; ++i) s_ += __expf(v_[i] - m_);                 \
    _Pragma("unroll")                                                      \
    for (int off = 32; off > 0; off >>= 1) s_ += __shfl_xor(s_, off);      \
    labs[j_] = am_; ms[j_] = m_; lse[j_] = logf(s_);                       \
  }

// One wave per batch element; 4 waves/block. Each block writes one partial
// (no global atomics -- 32768 same-address atomicAdds were the R0 bottleneck).
__global__ __launch_bounds__(256) void self_loss_partial(
    const float* __restrict__ logits, float* __restrict__ ws, int B) {
  const int wave = threadIdx.x >> 6;
  const int lane = threadIdx.x & 63;
  const int b = blockIdx.x * 4 + wave;

  __shared__ float sm[4];
  float wave_loss = 0.f;

  if (b < B) {
    int   labs[NUM_MODELS];
    float ms[NUM_MODELS];
    float lse[NUM_MODELS];

    float va[16], vb[16];
    LOAD_ROW(0, va);
    #pragma unroll
    for (int j = 0; j < NUM_MODELS; ++j) {
      if ((j & 1) == 0) {
        if (j + 1 < NUM_MODELS) LOAD_ROW(j + 1, vb);  // prefetch overlaps reduce
        PROCESS_ROW(j, va);
      } else {
        if (j + 1 < NUM_MODELS) LOAD_ROW(j + 1, va);
        PROCESS_ROW(j, vb);
      }
    }

    // Exact reference vote: after model j, its label's count is
    // c = 1 + #{k<j : lab_k==lab_j}; winner updates only on c > best.
    int best_label = 0, best_count = 0;
    #pragma unroll
    for (int j = 0; j < NUM_MODELS; ++j) {
      int c = 1;
      #pragma unroll
      for (int k = 0; k < j; ++k) c += (labs[k] == labs[j]) ? 1 : 0;
      if (c > best_count) { best_count = c; best_label = labs[j]; }
    }

    // Gather logits[j,b,pred] (row was just read -> L2/L3 hit).
    float picked = 0.f;
    if (lane < NUM_MODELS)
      picked = logits[((size_t)lane * B + b) * LABELS + best_label];

    float tot = 0.f;
    #pragma unroll
    for (int j = 0; j < NUM_MODELS; ++j)
      tot += __shfl(picked, j) - ms[j] - lse[j];

    wave_loss = -tot / (float)B;
  }

  if (lane == 0) sm[wave] = wave_loss;
  __syncthreads();
  if (threadIdx.x == 0)
    ws[blockIdx.x] = sm[0] + sm[1] + sm[2] + sm[3];
}

// Single-block deterministic sum of the per-block partials.
__global__ __launch_bounds__(256) void self_loss_reduce(
    const float* __restrict__ ws, float* __restrict__ out, int n) {
  __shared__ float sm[4];
  float s = 0.f;
  for (int i = threadIdx.x; i < n; i += 256) s += ws[i];
  #pragma unroll
  for (int off = 32; off > 0; off >>= 1) s += __shfl_xor(s, off);
  if ((threadIdx.x & 63) == 0) sm[threadIdx.x >> 6] = s;
  __syncthreads();
  if (threadIdx.x == 0) out[0] = sm[0] + sm[1] + sm[2] + sm[3];
}

extern "C" void kernel_launch(void* const* d_in, const int* in_sizes, int n_in,
                              void* d_out, int out_size, void* d_ws, size_t ws_size,
                              hipStream_t stream) {
  const float* logits = (const float*)d_in[0];
  float* out = (float*)d_out;
  float* ws = (float*)d_ws;
  const int n = in_sizes[0];
  const int B = n / (NUM_MODELS * LABELS);

  const int blocks = (B + 3) / 4;  // 8192 for B=32768 (needs 32 KiB of ws)
  self_loss_partial<<<blocks, 256, 0, stream>>>(logits, ws, B);
  self_loss_reduce<<<1, 256, 0, stream>>>(ws, out, blocks);
}